// Round 11
// baseline (621.416 us; speedup 1.0000x reference)
//
#include <hip/hip_runtime.h>
#include <hip/hip_bf16.h>

// DiagonalWindowAttention (v8: fused, A-fragments in registers, LDS 32.8 KB).
//   build_comb : comb[mi][n][q][k] = mask + rel-pos bias (d_ws)
//   dwa_v8     : one block per window, 256 thr, LB(256,3), 3 blocks/CU:
//     phase 0 : q full load -> LN stats -> LN+pack to 12 uint4 regs;
//               prefetch head-0 k/v.
//     head n  : stage Q/K (swz [64][64]) + VT (transposed); prefetch n+1;
//               comb -> sacc; BAR; QK^T MFMA (C=comb); softmax in place;
//               P over Q0 (wave-private, fence); PV MFMA; PRS transpose
//               (wave-private, fence); collect proj A-frags into regs
//               (lane keeps its head-parity slice); BAR.
//     epilogue: per ct {build W B-frags, 4 mt x 3 MFMA, +bias, stores}.
//               No LDS use, no barrier, no global scratch.
//
// token grouping: p = wh*8+ww, s = sh*2+sw, seq g = wh*32+sh*16+ww*2+sw

#define TPB 256

// LDS byte offsets
#define Q0   0        // [64][64] bf16 swizzled (8 KB); P overlays after QK^T
#define K0   8192
#define VT0  16384    // V^T per head (8 KB)
#define PRS0 24576    // [2][256][8] bf16 transpose staging (8 KB), wave-private rows
#define V8_LDS 32768

typedef __attribute__((ext_vector_type(8))) short short8;
typedef __attribute__((ext_vector_type(4))) float f32x4;

union FRAG { uint4 u4; short8 s8; unsigned short us[8]; };

__device__ __forceinline__ int seq_of(int p, int s) {
    return ((p >> 3) << 5) | ((s >> 1) << 4) | ((p & 7) << 1) | (s & 1);
}

#define SWZ(row, slot) (((row) << 7) + ((((slot) ^ ((row) & 7))) << 4))

#define LGKM_FENCE() do { \
    asm volatile("s_waitcnt lgkmcnt(0)" ::: "memory"); \
    __builtin_amdgcn_sched_barrier(0); } while (0)

// stage-complete barrier: drain LDS writes, sync; vmcnt stays in flight
#define BAR_STAGE() do { \
    asm volatile("s_waitcnt lgkmcnt(0)" ::: "memory"); \
    __builtin_amdgcn_sched_barrier(0); \
    __builtin_amdgcn_s_barrier(); \
    __builtin_amdgcn_sched_barrier(0); } while (0)

// end-of-iteration barrier: LDS reads already retired via data deps
#define BAR_WAR() do { \
    __builtin_amdgcn_sched_barrier(0); \
    __builtin_amdgcn_s_barrier(); \
    __builtin_amdgcn_sched_barrier(0); } while (0)

__device__ __forceinline__ unsigned short f2b(float x) {
    union { __hip_bfloat16 h; unsigned short u; } z;
    z.h = __float2bfloat16(x);
    return z.u;
}

__device__ __forceinline__ uint4 pack8(const float* v) {
    union { uint4 u4; unsigned short us[8]; } z;
#pragma unroll
    for (int i = 0; i < 8; ++i) z.us[i] = f2b(v[i]);
    return z.u4;
}

__device__ __forceinline__ void load_pack(const float* src, uint4* dst) {
    float v[16];
#pragma unroll
    for (int i = 0; i < 4; ++i) {
        float4 x = ((const float4*)src)[i];
        v[4 * i] = x.x; v[4 * i + 1] = x.y; v[4 * i + 2] = x.z; v[4 * i + 3] = x.w;
    }
    dst[0] = pack8(v);
    dst[1] = pack8(v + 8);
}

// ---------------- pre-kernel: comb = mask + rel-pos bias ----------------
__global__ void build_comb(const float* __restrict__ gmask,
                           const float* __restrict__ gbt,
                           float* __restrict__ comb) {
    const int b = blockIdx.x;            // b = mi*6 + n
    const int mi = b / 6, n = b - mi * 6;
    const int t = threadIdx.x;
    const float* mrow = gmask + (size_t)mi * 4096;
    float* crow = comb + (size_t)b * 4096;
#pragma unroll
    for (int e = 0; e < 4096; e += TPB) {
        const int i = e + t;
        const int q = i >> 6, k = i & 63;
        const int idx = ((q >> 3) - (k >> 3) + 7) * 15 + ((q & 7) - (k & 7) + 7);
        crow[i] = mrow[i] + gbt[idx * 6 + n];
    }
}

// ============================ v8 main kernel ============================
template <int USE_COMB>
__global__ __launch_bounds__(TPB, 3)
void dwa_v8(const float* __restrict__ gq,
            const float* __restrict__ gk,
            const float* __restrict__ gv,
            const float* __restrict__ gmask,
            const float* __restrict__ gbt,
            const float* __restrict__ ggamma,
            const float* __restrict__ gbeta,
            const float* __restrict__ gpw,
            const float* __restrict__ gpb,
            float* __restrict__ gout,
            const float* __restrict__ comb,
            int nwm)
{
    __shared__ __align__(16) unsigned char Lraw[V8_LDS];
    char* L = (char*)Lraw;

    const int w = blockIdx.x;
    const int t = threadIdx.x;
    const int lane = t & 63, wv = t >> 6;
    const int r15 = lane & 15, gsl = lane >> 4;

    const int p_a = t >> 2, s_a = t & 3;
    const int g_a = seq_of(p_a, s_a);
    const size_t rowbase = ((size_t)w * 256 + g_a) * 96;
    const int mbase = (w % nwm) * 4096;
    const int qr0 = (wv << 4) + (gsl << 2);
    const f32x4 zf = {0.f, 0.f, 0.f, 0.f};

    // ---------- phase 0: q full load, LN stats, LN+pack to 12 uint4 ----------
    uint4 qreg[12];
    {
        float qv[96];
        float sum = 0.f, ssq = 0.f;
        const float4* qr4 = (const float4*)(gq + rowbase);
#pragma unroll
        for (int i = 0; i < 24; ++i) {
            float4 x = qr4[i];
            qv[4 * i] = x.x; qv[4 * i + 1] = x.y;
            qv[4 * i + 2] = x.z; qv[4 * i + 3] = x.w;
            sum += (x.x + x.y) + (x.z + x.w);
            ssq += (x.x * x.x + x.y * x.y) + (x.z * x.z + x.w * x.w);
        }
        sum += __shfl_xor(sum, 1); ssq += __shfl_xor(ssq, 1);
        sum += __shfl_xor(sum, 2); ssq += __shfl_xor(ssq, 2);
        const float mu = sum * (1.f / 384.f);
        const float rs = rsqrtf(ssq * (1.f / 384.f) - mu * mu + 1e-5f);
        const float4* ga4 = (const float4*)(ggamma + s_a * 96);
        const float4* be4 = (const float4*)(gbeta + s_a * 96);
#pragma unroll
        for (int c6 = 0; c6 < 6; ++c6) {
            float vals[16];
#pragma unroll
            for (int j = 0; j < 4; ++j) {
                float4 g = ga4[c6 * 4 + j];
                float4 b = be4[c6 * 4 + j];
                const int base = c6 * 16 + 4 * j;
                vals[4 * j + 0] = ((qv[base + 0] - mu) * rs * g.x + b.x) * 0.125f;
                vals[4 * j + 1] = ((qv[base + 1] - mu) * rs * g.y + b.y) * 0.125f;
                vals[4 * j + 2] = ((qv[base + 2] - mu) * rs * g.z + b.z) * 0.125f;
                vals[4 * j + 3] = ((qv[base + 3] - mu) * rs * g.w + b.w) * 0.125f;
            }
            qreg[2 * c6]     = pack8(vals);
            qreg[2 * c6 + 1] = pack8(vals + 8);
        }
    }
    uint4 kpf[2][2], vpf[2][2];
    load_pack(gk + rowbase, kpf[0]);
    load_pack(gv + rowbase, vpf[0]);

    // projection A-fragments, accumulated across heads (wave-private pre in regs)
    FRAG A[4][3];
#pragma unroll
    for (int mt = 0; mt < 4; ++mt)
#pragma unroll
        for (int kk = 0; kk < 3; ++kk)
            A[mt][kk].u4 = make_uint4(0, 0, 0, 0);

    // ----------------------------- head loop -----------------------------
#pragma unroll
    for (int n = 0; n < 6; ++n) {
        // stage Q (regs), K, VT (transposed)
        *(uint4*)(L + Q0 + SWZ(p_a, s_a * 2))     = qreg[2 * n];
        *(uint4*)(L + Q0 + SWZ(p_a, s_a * 2 + 1)) = qreg[2 * n + 1];
        *(uint4*)(L + K0 + SWZ(p_a, s_a * 2))     = kpf[n & 1][0];
        *(uint4*)(L + K0 + SWZ(p_a, s_a * 2 + 1)) = kpf[n & 1][1];
#pragma unroll
        for (int h = 0; h < 2; ++h) {
            FRAG u; u.u4 = vpf[n & 1][h];
#pragma unroll
            for (int c = 0; c < 8; ++c) {
                const int np_ = s_a * 16 + h * 8 + c;
                *(unsigned short*)(L + VT0 + (np_ << 7) +
                    ((((p_a >> 3) ^ (np_ & 7))) << 4) + ((p_a & 7) << 1)) = u.us[c];
            }
        }
        // prefetch next head's k/v (in flight across the barrier)
        if (n < 5) {
            load_pack(gk + rowbase + (n + 1) * 16, kpf[(n + 1) & 1]);
            load_pack(gv + rowbase + (n + 1) * 16, vpf[(n + 1) & 1]);
        }
        // C init = comb (bias+mask)
        f32x4 sacc[4];
        if (USE_COMB) {
            const float* cb = comb + (size_t)((w % nwm) * 6 + n) * 4096;
#pragma unroll
            for (int tile = 0; tile < 4; ++tile)
#pragma unroll
                for (int r = 0; r < 4; ++r)
                    sacc[tile][r] = cb[((qr0 + r) << 6) + (tile << 4) + r15];
        } else {
#pragma unroll
            for (int tile = 0; tile < 4; ++tile) {
                const int kpx = (tile << 4) + r15;
                const int ik = kpx >> 3, jk = kpx & 7;
#pragma unroll
                for (int r = 0; r < 4; ++r) {
                    const int q = qr0 + r;
                    sacc[tile][r] = gbt[(((q >> 3) - ik + 7) * 15 + ((q & 7) - jk + 7)) * 6 + n]
                                  + gmask[mbase + (q << 6) + kpx];
                }
            }
        }
        BAR_STAGE();

        // QK^T
        {
            FRAG a0, a1;
            a0.u4 = *(const uint4*)(L + Q0 + SWZ(wv * 16 + r15, gsl));
            a1.u4 = *(const uint4*)(L + Q0 + SWZ(wv * 16 + r15, 4 + gsl));
#pragma unroll
            for (int tile = 0; tile < 4; ++tile) {
                FRAG b0, b1;
                b0.u4 = *(const uint4*)(L + K0 + SWZ(tile * 16 + r15, gsl));
                b1.u4 = *(const uint4*)(L + K0 + SWZ(tile * 16 + r15, 4 + gsl));
                sacc[tile] = __builtin_amdgcn_mfma_f32_16x16x32_bf16(a0.s8, b0.s8, sacc[tile], 0, 0, 0);
                sacc[tile] = __builtin_amdgcn_mfma_f32_16x16x32_bf16(a1.s8, b1.s8, sacc[tile], 0, 0, 0);
            }
        }

        // softmax in place; P overlays Q0 (wave-private rows)
#pragma unroll
        for (int r = 0; r < 4; ++r) {
            const int q = qr0 + r;
            float mx = fmaxf(fmaxf(sacc[0][r], sacc[1][r]),
                             fmaxf(sacc[2][r], sacc[3][r]));
            mx = fmaxf(mx, __shfl_xor(mx, 1));
            mx = fmaxf(mx, __shfl_xor(mx, 2));
            mx = fmaxf(mx, __shfl_xor(mx, 4));
            mx = fmaxf(mx, __shfl_xor(mx, 8));
            float sm = 0.f;
#pragma unroll
            for (int tile = 0; tile < 4; ++tile) {
                sacc[tile][r] = __expf(sacc[tile][r] - mx);
                sm += sacc[tile][r];
            }
            sm += __shfl_xor(sm, 1);
            sm += __shfl_xor(sm, 2);
            sm += __shfl_xor(sm, 4);
            sm += __shfl_xor(sm, 8);
            const float inv = 1.0f / sm;
#pragma unroll
            for (int tile = 0; tile < 4; ++tile) {
                const int col = (tile << 4) + r15;
                *(unsigned short*)(L + Q0 + (q << 7) +
                                   (((col >> 3) ^ (q & 7)) << 4) + ((col & 7) << 1))
                    = f2b(sacc[tile][r] * inv);
            }
        }
        LGKM_FENCE();

        // PV
        f32x4 oacc[4];
        {
            FRAG pa0, pa1;
            pa0.u4 = *(const uint4*)(L + Q0 + SWZ(wv * 16 + r15, gsl));
            pa1.u4 = *(const uint4*)(L + Q0 + SWZ(wv * 16 + r15, 4 + gsl));
#pragma unroll
            for (int ct = 0; ct < 4; ++ct) {
                FRAG b0, b1;
                b0.u4 = *(const uint4*)(L + VT0 + SWZ(ct * 16 + r15, gsl));
                b1.u4 = *(const uint4*)(L + VT0 + SWZ(ct * 16 + r15, 4 + gsl));
                oacc[ct] = __builtin_amdgcn_mfma_f32_16x16x32_bf16(pa0.s8, b0.s8, zf, 0, 0, 0);
                oacc[ct] = __builtin_amdgcn_mfma_f32_16x16x32_bf16(pa1.s8, b1.s8, oacc[ct], 0, 0, 0);
            }
        }

        // transpose via PRS: [h2=r15>>3][tok][r15&7] (wave-private rows)
#pragma unroll
        for (int ct = 0; ct < 4; ++ct)
#pragma unroll
            for (int r = 0; r < 4; ++r) {
                const int tok = ((qr0 + r) << 2) + ct;
                *(unsigned short*)(L + PRS0 + ((r15 >> 3) << 12) + (tok << 4) +
                                   ((r15 & 7) << 1)) = f2b(oacc[ct][r]);
            }
        LGKM_FENCE();

        // collect projection A-frags: lane keeps its slice iff gsl>>1 == n&1
        {
            const bool keep = ((gsl >> 1) == (n & 1));
            const int prsb = PRS0 + ((gsl & 1) << 12);
#pragma unroll
            for (int mt = 0; mt < 4; ++mt) {
                const int tok = (wv << 6) + (mt << 4) + r15;
                uint4 v = *(const uint4*)(L + prsb + (tok << 4));
                A[mt][n >> 1].u4.x = keep ? v.x : A[mt][n >> 1].u4.x;
                A[mt][n >> 1].u4.y = keep ? v.y : A[mt][n >> 1].u4.y;
                A[mt][n >> 1].u4.z = keep ? v.z : A[mt][n >> 1].u4.z;
                A[mt][n >> 1].u4.w = keep ? v.w : A[mt][n >> 1].u4.w;
            }
        }
        BAR_WAR();
    }

    // ---- epilogue: projection from register A-frags (no LDS, no barrier) ----
    {
#pragma unroll
        for (int ct = 0; ct < 6; ++ct) {
            const int o = (ct << 4) + r15;
            const float pbv = gpb[o];
            FRAG bw[3];
#pragma unroll
            for (int kk = 0; kk < 3; ++kk) {
                const float4* wp = (const float4*)(gpw + o * 96 + kk * 32 + (gsl << 3));
                float4 w0 = wp[0], w1 = wp[1];
                float w8[8] = {w0.x, w0.y, w0.z, w0.w, w1.x, w1.y, w1.z, w1.w};
                bw[kk].u4 = pack8(w8);
            }
#pragma unroll
            for (int mt = 0; mt < 4; ++mt) {
                f32x4 acc;
                acc = __builtin_amdgcn_mfma_f32_16x16x32_bf16(A[mt][0].s8, bw[0].s8, zf, 0, 0, 0);
                acc = __builtin_amdgcn_mfma_f32_16x16x32_bf16(A[mt][1].s8, bw[1].s8, acc, 0, 0, 0);
                acc = __builtin_amdgcn_mfma_f32_16x16x32_bf16(A[mt][2].s8, bw[2].s8, acc, 0, 0, 0);
#pragma unroll
                for (int rr = 0; rr < 4; ++rr) {
                    const int token = (wv << 6) + (mt << 4) + (gsl << 2) + rr;
                    const int p = token >> 2, s = token & 3;
                    const int gsq = seq_of(p, s);
                    gout[((size_t)w * 256 + gsq) * 96 + o] = acc[rr] + pbv;
                }
            }
        }
    }
}

extern "C" void kernel_launch(void* const* d_in, const int* in_sizes, int n_in,
                              void* d_out, int out_size, void* d_ws, size_t ws_size,
                              hipStream_t stream) {
    const float* gq     = (const float*)d_in[0];
    const float* gk     = (const float*)d_in[1];
    const float* gv     = (const float*)d_in[2];
    const float* gmask  = (const float*)d_in[3];
    const float* gbt    = (const float*)d_in[4];
    const float* ggamma = (const float*)d_in[5];
    const float* gbeta  = (const float*)d_in[6];
    const float* gpw    = (const float*)d_in[7];
    const float* gpb    = (const float*)d_in[8];
    float* gout = (float*)d_out;

    const int nw  = in_sizes[0] / (256 * 96);
    const int nwm = in_sizes[3] / (64 * 64);
    const size_t comb_bytes = (size_t)nwm * 6 * 4096 * sizeof(float);

    if (ws_size >= comb_bytes) {
        float* comb = (float*)d_ws;
        build_comb<<<nwm * 6, TPB, 0, stream>>>(gmask, gbt, comb);
        dwa_v8<1><<<nw, TPB, 0, stream>>>(gq, gk, gv, gmask, gbt, ggamma, gbeta,
                                          gpw, gpb, gout, comb, nwm);
    } else {
        dwa_v8<0><<<nw, TPB, 0, stream>>>(gq, gk, gv, gmask, gbt, ggamma, gbeta,
                                          gpw, gpb, gout, (const float*)nullptr, nwm);
    }
}

// Round 12
// 410.020 us; speedup vs baseline: 1.5156x; 1.5156x over previous
//
#include <hip/hip_runtime.h>
#include <hip/hip_bf16.h>

// DiagonalWindowAttention (v9 = r7 base + swapped QK^T softmax).
//   build_comb : combT[mi][n][k][q] = mask[q][k] + rel-pos bias[q][k] (d_ws)
//   dwa_mfma   : one block per window, 256 thr, LB(256,2), LDS 76 KB:
//     phase 0 : q full load -> LN stats -> LN+pack to 12 uint4 regs;
//               prefetch head-0 k/v.
//     head n  : stage Q/K (swz [64][64]) + VT (transposed, SV-swz); prefetch
//               n+1; combT -> sacc; sync; QK^T SWAPPED mfma(A=K, B=Q) ->
//               D[k][q]: each lane holds 16 k-values of ONE q -> softmax =
//               in-lane reduce + 2 shfl; P store 4x ds_write_b64 over Q0
//               (wave-private rows, fence); PV mfma(A=P, B=VT); PR store; sync.
//     epilogue: deferred 256x96x96 projection from PR (per-wave M-tiles).
//
// token grouping: p = wh*8+ww, s = sh*2+sw, seq g = wh*32+sh*16+ww*2+sw

#define TPB 256

// LDS byte offsets
#define Q0   0        // [64][64] bf16 swizzled (8 KB); P overlays after QK^T
#define K0   8192
#define VT0  16384    // V^T per head (8 KB), SV-swizzled
#define PR0  24576    // pre[256 tokens][104 shorts] (208 B rows) = 53248 B
#define V_LDS 77824

typedef __attribute__((ext_vector_type(8))) short short8;
typedef __attribute__((ext_vector_type(4))) float f32x4;

union FRAG { uint4 u4; short8 s8; unsigned short us[8]; };

__device__ __forceinline__ int seq_of(int p, int s) {
    return ((p >> 3) << 5) | ((s >> 1) << 4) | ((p & 7) << 1) | (s & 1);
}

// swizzled byte address of 16B slot in a [64][64] bf16 tile (128B rows)
#define SWZ(row, slot) (((row) << 7) + ((((slot) ^ ((row) & 7))) << 4))
// VT swizzle key (spreads banks across s/h/c during staging writes)
#define SVK(n) (((n) ^ ((n) >> 3)) & 7)

#define LGKM_FENCE() do { \
    asm volatile("s_waitcnt lgkmcnt(0)" ::: "memory"); \
    __builtin_amdgcn_sched_barrier(0); } while (0)

__device__ __forceinline__ unsigned short f2b(float x) {
    union { __hip_bfloat16 h; unsigned short u; } z;
    z.h = __float2bfloat16(x);
    return z.u;
}

__device__ __forceinline__ uint4 pack8(const float* v) {
    union { uint4 u4; unsigned short us[8]; } z;
#pragma unroll
    for (int i = 0; i < 8; ++i) z.us[i] = f2b(v[i]);
    return z.u4;
}

__device__ __forceinline__ void load_pack(const float* src, uint4* dst) {
    float v[16];
#pragma unroll
    for (int i = 0; i < 4; ++i) {
        float4 x = ((const float4*)src)[i];
        v[4 * i] = x.x; v[4 * i + 1] = x.y; v[4 * i + 2] = x.z; v[4 * i + 3] = x.w;
    }
    dst[0] = pack8(v);
    dst[1] = pack8(v + 8);
}

// -------- pre-kernel: combT[k][q] = mask[q][k] + bias[q][k] (transposed) ------
__global__ void build_comb(const float* __restrict__ gmask,
                           const float* __restrict__ gbt,
                           float* __restrict__ comb) {
    const int b = blockIdx.x;            // b = mi*6 + n
    const int mi = b / 6, n = b - mi * 6;
    const int t = threadIdx.x;
    const float* mrow = gmask + (size_t)mi * 4096;
    float* crow = comb + (size_t)b * 4096;
    __shared__ float mt_[64 * 65];
#pragma unroll
    for (int e = 0; e < 4096; e += TPB) {
        const int i = e + t;
        mt_[(i >> 6) * 65 + (i & 63)] = mrow[i];   // mt_[q][k]
    }
    __syncthreads();
#pragma unroll
    for (int e = 0; e < 4096; e += TPB) {
        const int i = e + t;
        const int k = i >> 6, q = i & 63;
        const int idx = ((q >> 3) - (k >> 3) + 7) * 15 + ((q & 7) - (k & 7) + 7);
        crow[i] = mt_[q * 65 + k] + gbt[idx * 6 + n];   // crow[k][q]
    }
}

// ============================ main kernel ============================
template <int USE_COMB>
__global__ __launch_bounds__(TPB, 2)
void dwa_mfma(const float* __restrict__ gq,
              const float* __restrict__ gk,
              const float* __restrict__ gv,
              const float* __restrict__ gmask,
              const float* __restrict__ gbt,
              const float* __restrict__ ggamma,
              const float* __restrict__ gbeta,
              const float* __restrict__ gpw,
              const float* __restrict__ gpb,
              float* __restrict__ gout,
              const float* __restrict__ comb,
              int nwm)
{
    __shared__ __align__(16) unsigned char Lraw[V_LDS];
    char* L = (char*)Lraw;

    const int w = blockIdx.x;
    const int t = threadIdx.x;
    const int lane = t & 63, wv = t >> 6;
    const int r15 = lane & 15, gsl = lane >> 4;

    const int p_a = t >> 2, s_a = t & 3;
    const int g_a = seq_of(p_a, s_a);
    const size_t rowbase = ((size_t)w * 256 + g_a) * 96;
    const int mbase = (w % nwm) * 4096;
    const int qr0 = (wv << 4) + (gsl << 2);      // C-layout q-row base (PV/PR)
    const int qcol = (wv << 4) + r15;            // this lane's q (swapped QK^T)
    const f32x4 zf = {0.f, 0.f, 0.f, 0.f};

    // ---------- phase 0: q full load, LN stats, LN+pack to 12 uint4 ----------
    uint4 qreg[12];
    {
        float qv[96];
        float sum = 0.f, ssq = 0.f;
        const float4* qr4 = (const float4*)(gq + rowbase);
#pragma unroll
        for (int i = 0; i < 24; ++i) {
            float4 x = qr4[i];
            qv[4 * i] = x.x; qv[4 * i + 1] = x.y;
            qv[4 * i + 2] = x.z; qv[4 * i + 3] = x.w;
            sum += (x.x + x.y) + (x.z + x.w);
            ssq += (x.x * x.x + x.y * x.y) + (x.z * x.z + x.w * x.w);
        }
        sum += __shfl_xor(sum, 1); ssq += __shfl_xor(ssq, 1);
        sum += __shfl_xor(sum, 2); ssq += __shfl_xor(ssq, 2);
        const float mu = sum * (1.f / 384.f);
        const float rs = rsqrtf(ssq * (1.f / 384.f) - mu * mu + 1e-5f);
        const float4* ga4 = (const float4*)(ggamma + s_a * 96);
        const float4* be4 = (const float4*)(gbeta + s_a * 96);
#pragma unroll
        for (int c6 = 0; c6 < 6; ++c6) {
            float vals[16];
#pragma unroll
            for (int j = 0; j < 4; ++j) {
                float4 g = ga4[c6 * 4 + j];
                float4 b = be4[c6 * 4 + j];
                const int base = c6 * 16 + 4 * j;
                vals[4 * j + 0] = ((qv[base + 0] - mu) * rs * g.x + b.x) * 0.125f;
                vals[4 * j + 1] = ((qv[base + 1] - mu) * rs * g.y + b.y) * 0.125f;
                vals[4 * j + 2] = ((qv[base + 2] - mu) * rs * g.z + b.z) * 0.125f;
                vals[4 * j + 3] = ((qv[base + 3] - mu) * rs * g.w + b.w) * 0.125f;
            }
            qreg[2 * c6]     = pack8(vals);
            qreg[2 * c6 + 1] = pack8(vals + 8);
        }
    }
    uint4 kpf[2][2], vpf[2][2];
    load_pack(gk + rowbase, kpf[0]);
    load_pack(gv + rowbase, vpf[0]);

    // ----------------------------- head loop -----------------------------
#pragma unroll
    for (int n = 0; n < 6; ++n) {
        // stage Q (regs), K, VT (transposed, SV swizzle)
        *(uint4*)(L + Q0 + SWZ(p_a, s_a * 2))     = qreg[2 * n];
        *(uint4*)(L + Q0 + SWZ(p_a, s_a * 2 + 1)) = qreg[2 * n + 1];
        *(uint4*)(L + K0 + SWZ(p_a, s_a * 2))     = kpf[n & 1][0];
        *(uint4*)(L + K0 + SWZ(p_a, s_a * 2 + 1)) = kpf[n & 1][1];
#pragma unroll
        for (int h = 0; h < 2; ++h) {
            FRAG u; u.u4 = vpf[n & 1][h];
#pragma unroll
            for (int c = 0; c < 8; ++c) {
                const int np_ = s_a * 16 + h * 8 + c;   // n' row of VT
                *(unsigned short*)(L + VT0 + (np_ << 7) +
                    (((p_a >> 3) ^ SVK(np_)) << 4) + ((p_a & 7) << 1)) = u.us[c];
            }
        }
        // prefetch next head's k/v (in flight across the barrier)
        if (n < 5) {
            load_pack(gk + rowbase + (n + 1) * 16, kpf[(n + 1) & 1]);
            load_pack(gv + rowbase + (n + 1) * 16, vpf[(n + 1) & 1]);
        }
        // C init = combT[k][q]  (bias+mask, transposed for swapped QK^T)
        f32x4 sacc[4];
        if (USE_COMB) {
            const float* cb = comb + (size_t)((w % nwm) * 6 + n) * 4096 + qcol;
#pragma unroll
            for (int mt = 0; mt < 4; ++mt)
#pragma unroll
                for (int r = 0; r < 4; ++r)
                    sacc[mt][r] = cb[((mt << 4) + (gsl << 2) + r) << 6];
        } else {
            const int iq = qcol >> 3, jq = qcol & 7;
#pragma unroll
            for (int mt = 0; mt < 4; ++mt)
#pragma unroll
                for (int r = 0; r < 4; ++r) {
                    const int k = (mt << 4) + (gsl << 2) + r;
                    sacc[mt][r] = gbt[((iq - (k >> 3) + 7) * 15 + (jq - (k & 7) + 7)) * 6 + n]
                                + gmask[mbase + (qcol << 6) + k];
                }
        }
        __syncthreads();                     // barrier 1: staging visible

        // QK^T SWAPPED: sacc[mt] = D[k = 16mt+4gsl+r][q = qcol]
        {
            FRAG qf0, qf1;
            qf0.u4 = *(const uint4*)(L + Q0 + SWZ(qcol, gsl));
            qf1.u4 = *(const uint4*)(L + Q0 + SWZ(qcol, 4 + gsl));
#pragma unroll
            for (int mt = 0; mt < 4; ++mt) {
                FRAG kf0, kf1;
                kf0.u4 = *(const uint4*)(L + K0 + SWZ(mt * 16 + r15, gsl));
                kf1.u4 = *(const uint4*)(L + K0 + SWZ(mt * 16 + r15, 4 + gsl));
                sacc[mt] = __builtin_amdgcn_mfma_f32_16x16x32_bf16(kf0.s8, qf0.s8, sacc[mt], 0, 0, 0);
                sacc[mt] = __builtin_amdgcn_mfma_f32_16x16x32_bf16(kf1.s8, qf1.s8, sacc[mt], 0, 0, 0);
            }
        }

        // softmax: lane holds full k-range slice of ONE q -> in-lane + 2 shfl
        {
            float mx = sacc[0][0];
#pragma unroll
            for (int mt = 0; mt < 4; ++mt)
#pragma unroll
                for (int r = 0; r < 4; ++r) mx = fmaxf(mx, sacc[mt][r]);
            mx = fmaxf(mx, __shfl_xor(mx, 16));
            mx = fmaxf(mx, __shfl_xor(mx, 32));
            float sm = 0.f;
#pragma unroll
            for (int mt = 0; mt < 4; ++mt)
#pragma unroll
                for (int r = 0; r < 4; ++r) {
                    sacc[mt][r] = __expf(sacc[mt][r] - mx);
                    sm += sacc[mt][r];
                }
            sm += __shfl_xor(sm, 16);
            sm += __shfl_xor(sm, 32);
            const float inv = 1.0f / sm;
            // P store over Q0: row q = qcol (wave-private AND lane-consistent)
            const int qb = qcol << 7, qx = qcol & 7;
#pragma unroll
            for (int mt = 0; mt < 4; ++mt) {
                unsigned u0 = (unsigned)f2b(sacc[mt][0] * inv)
                            | ((unsigned)f2b(sacc[mt][1] * inv) << 16);
                unsigned u1 = (unsigned)f2b(sacc[mt][2] * inv)
                            | ((unsigned)f2b(sacc[mt][3] * inv) << 16);
                const int slot = (mt << 1) + (gsl >> 1);
                *(uint2*)(L + Q0 + qb + (((slot ^ qx)) << 4) + ((gsl & 1) << 3))
                    = make_uint2(u0, u1);
            }
        }
        LGKM_FENCE();                        // P rows are wave-private

        // PV: A = P (rows = wave's q), B = VT rows (SV swizzle)
        f32x4 oacc[4];
        {
            FRAG pa0, pa1;
            pa0.u4 = *(const uint4*)(L + Q0 + SWZ(qcol, gsl));
            pa1.u4 = *(const uint4*)(L + Q0 + SWZ(qcol, 4 + gsl));
#pragma unroll
            for (int ct = 0; ct < 4; ++ct) {
                const int nr = ct * 16 + r15;
                const int sv = SVK(nr);
                FRAG b0, b1;
                b0.u4 = *(const uint4*)(L + VT0 + (nr << 7) + ((gsl ^ sv) << 4));
                b1.u4 = *(const uint4*)(L + VT0 + (nr << 7) + (((4 + gsl) ^ sv) << 4));
                oacc[ct] = __builtin_amdgcn_mfma_f32_16x16x32_bf16(pa0.s8, b0.s8, zf, 0, 0, 0);
                oacc[ct] = __builtin_amdgcn_mfma_f32_16x16x32_bf16(pa1.s8, b1.s8, oacc[ct], 0, 0, 0);
            }
        }

        // pre[token = q*4 + s][ n*16 + hd ] into PR (208 B rows, wave-private)
#pragma unroll
        for (int ct = 0; ct < 4; ++ct)
#pragma unroll
            for (int r = 0; r < 4; ++r) {
                const int token = ((qr0 + r) << 2) + ct;
                *(unsigned short*)(L + PR0 + token * 208 + ((n << 4) + r15) * 2)
                    = f2b(oacc[ct][r]);
            }
        __syncthreads();                     // barrier 2: cross-wave reads done
    }

    // ------ epilogue: deferred projection, 4 sequential M-tiles per wave ------
    {
        FRAG bw[3][6];
#pragma unroll
        for (int kk = 0; kk < 3; ++kk)
#pragma unroll
            for (int ct = 0; ct < 6; ++ct) {
                const int o = (ct << 4) + r15;
                const float4* wp = (const float4*)(gpw + o * 96 + kk * 32 + (gsl << 3));
                float4 w0 = wp[0], w1 = wp[1];
                float w8[8] = {w0.x, w0.y, w0.z, w0.w, w1.x, w1.y, w1.z, w1.w};
                bw[kk][ct].u4 = pack8(w8);
            }
        float pbv[6];
#pragma unroll
        for (int ct = 0; ct < 6; ++ct) pbv[ct] = gpb[(ct << 4) + r15];

#pragma unroll
        for (int mt = 0; mt < 4; ++mt) {
            const int rowA = (wv << 6) + (mt << 4) + r15;
            FRAG A[3];
#pragma unroll
            for (int kk = 0; kk < 3; ++kk)
                A[kk].u4 = *(const uint4*)(L + PR0 + rowA * 208 + kk * 64 + (gsl << 4));
            f32x4 acc[6];
#pragma unroll
            for (int ct = 0; ct < 6; ++ct) {
                acc[ct] = __builtin_amdgcn_mfma_f32_16x16x32_bf16(A[0].s8, bw[0][ct].s8, zf, 0, 0, 0);
                acc[ct] = __builtin_amdgcn_mfma_f32_16x16x32_bf16(A[1].s8, bw[1][ct].s8, acc[ct], 0, 0, 0);
                acc[ct] = __builtin_amdgcn_mfma_f32_16x16x32_bf16(A[2].s8, bw[2][ct].s8, acc[ct], 0, 0, 0);
            }
#pragma unroll
            for (int ct = 0; ct < 6; ++ct)
#pragma unroll
                for (int rr = 0; rr < 4; ++rr) {
                    const int token = (wv << 6) + (mt << 4) + (gsl << 2) + rr;
                    const int p = token >> 2, s = token & 3;
                    const int gsq = seq_of(p, s);
                    gout[((size_t)w * 256 + gsq) * 96 + (ct << 4) + r15]
                        = acc[ct][rr] + pbv[ct];
                }
        }
    }
}

extern "C" void kernel_launch(void* const* d_in, const int* in_sizes, int n_in,
                              void* d_out, int out_size, void* d_ws, size_t ws_size,
                              hipStream_t stream) {
    const float* gq     = (const float*)d_in[0];
    const float* gk     = (const float*)d_in[1];
    const float* gv     = (const float*)d_in[2];
    const float* gmask  = (const float*)d_in[3];
    const float* gbt    = (const float*)d_in[4];
    const float* ggamma = (const float*)d_in[5];
    const float* gbeta  = (const float*)d_in[6];
    const float* gpw    = (const float*)d_in[7];
    const float* gpb    = (const float*)d_in[8];
    float* gout = (float*)d_out;

    const int nw  = in_sizes[0] / (256 * 96);
    const int nwm = in_sizes[3] / (64 * 64);
    const size_t comb_bytes = (size_t)nwm * 6 * 4096 * sizeof(float);

    if (ws_size >= comb_bytes) {
        float* comb = (float*)d_ws;
        build_comb<<<nwm * 6, TPB, 0, stream>>>(gmask, gbt, comb);
        dwa_mfma<1><<<nw, TPB, 0, stream>>>(gq, gk, gv, gmask, gbt, ggamma, gbeta,
                                            gpw, gpb, gout, comb, nwm);
    } else {
        dwa_mfma<0><<<nw, TPB, 0, stream>>>(gq, gk, gv, gmask, gbt, ggamma, gbeta,
                                            gpw, gpb, gout, (const float*)nullptr, nwm);
    }
}

// Round 13
// 279.876 us; speedup vs baseline: 2.2203x; 1.4650x over previous
//
#include <hip/hip_runtime.h>
#include <hip/hip_bf16.h>

// DiagonalWindowAttention (v10 = r7 base + lgkm-only raw barriers + early
// prefetch + SV-swizzled VT). One block per window, 256 thr, LB(256,2).
//   build_comb : comb[mi][n][q][k] = mask + rel-pos bias (d_ws)
//   head n  : issue k/v prefetch (n+1) -> stage Q/K (swz [64][64]) + VT
//             (transposed, SV-swz) -> comb -> sacc -> BAR(lgkm only; vmcnt
//             stays in flight) -> QK^T MFMA (C=comb) -> softmax -> P over Q0
//             (wave-private, fence) -> PV MFMA -> PR store -> BAR (skip @ n=5).
//   epilogue: deferred 256x96x96 projection from PR (per-wave M-tiles).
//
// token grouping: p = wh*8+ww, s = sh*2+sw, seq g = wh*32+sh*16+ww*2+sw

#define TPB 256

// LDS byte offsets
#define Q0   0        // [64][64] bf16 swizzled (8 KB); P overlays after QK^T
#define K0   8192
#define VT0  16384    // V^T per head (8 KB), SV-swizzled
#define PR0  24576    // pre[256 tokens][104 shorts] (208 B rows) = 53248 B
#define V_LDS 77824

typedef __attribute__((ext_vector_type(8))) short short8;
typedef __attribute__((ext_vector_type(4))) float f32x4;

union FRAG { uint4 u4; short8 s8; unsigned short us[8]; };

__device__ __forceinline__ int seq_of(int p, int s) {
    return ((p >> 3) << 5) | ((s >> 1) << 4) | ((p & 7) << 1) | (s & 1);
}

// swizzled byte address of 16B slot in a [64][64] bf16 tile (128B rows)
#define SWZ(row, slot) (((row) << 7) + ((((slot) ^ ((row) & 7))) << 4))
// VT swizzle key (spreads banks across n' during staging writes)
#define SVK(n) (((n) ^ ((n) >> 3)) & 7)

#define LGKM_FENCE() do { \
    asm volatile("s_waitcnt lgkmcnt(0)" ::: "memory"); \
    __builtin_amdgcn_sched_barrier(0); } while (0)

// stage-complete barrier: drain LDS writes + sync; vmcnt stays in flight
#define BAR_STAGE() do { \
    asm volatile("s_waitcnt lgkmcnt(0)" ::: "memory"); \
    __builtin_amdgcn_sched_barrier(0); \
    __builtin_amdgcn_s_barrier(); \
    __builtin_amdgcn_sched_barrier(0); } while (0)

// end-of-iteration barrier: this wave's LDS reads already retired (data deps)
#define BAR_WAR() do { \
    __builtin_amdgcn_sched_barrier(0); \
    __builtin_amdgcn_s_barrier(); \
    __builtin_amdgcn_sched_barrier(0); } while (0)

__device__ __forceinline__ unsigned short f2b(float x) {
    union { __hip_bfloat16 h; unsigned short u; } z;
    z.h = __float2bfloat16(x);
    return z.u;
}

__device__ __forceinline__ uint4 pack8(const float* v) {
    union { uint4 u4; unsigned short us[8]; } z;
#pragma unroll
    for (int i = 0; i < 8; ++i) z.us[i] = f2b(v[i]);
    return z.u4;
}

__device__ __forceinline__ void load_pack(const float* src, uint4* dst) {
    float v[16];
#pragma unroll
    for (int i = 0; i < 4; ++i) {
        float4 x = ((const float4*)src)[i];
        v[4 * i] = x.x; v[4 * i + 1] = x.y; v[4 * i + 2] = x.z; v[4 * i + 3] = x.w;
    }
    dst[0] = pack8(v);
    dst[1] = pack8(v + 8);
}

// ---------------- pre-kernel: comb = mask + rel-pos bias ----------------
__global__ void build_comb(const float* __restrict__ gmask,
                           const float* __restrict__ gbt,
                           float* __restrict__ comb) {
    const int b = blockIdx.x;            // b = mi*6 + n
    const int mi = b / 6, n = b - mi * 6;
    const int t = threadIdx.x;
    const float* mrow = gmask + (size_t)mi * 4096;
    float* crow = comb + (size_t)b * 4096;
#pragma unroll
    for (int e = 0; e < 4096; e += TPB) {
        const int i = e + t;
        const int q = i >> 6, k = i & 63;
        const int idx = ((q >> 3) - (k >> 3) + 7) * 15 + ((q & 7) - (k & 7) + 7);
        crow[i] = mrow[i] + gbt[idx * 6 + n];
    }
}

// ============================ main kernel ============================
template <int USE_COMB>
__global__ __launch_bounds__(TPB, 2)
void dwa_mfma(const float* __restrict__ gq,
              const float* __restrict__ gk,
              const float* __restrict__ gv,
              const float* __restrict__ gmask,
              const float* __restrict__ gbt,
              const float* __restrict__ ggamma,
              const float* __restrict__ gbeta,
              const float* __restrict__ gpw,
              const float* __restrict__ gpb,
              float* __restrict__ gout,
              const float* __restrict__ comb,
              int nwm)
{
    __shared__ __align__(16) unsigned char Lraw[V_LDS];
    char* L = (char*)Lraw;

    const int w = blockIdx.x;
    const int t = threadIdx.x;
    const int lane = t & 63, wv = t >> 6;
    const int r15 = lane & 15, gsl = lane >> 4;

    const int p_a = t >> 2, s_a = t & 3;
    const int g_a = seq_of(p_a, s_a);
    const size_t rowbase = ((size_t)w * 256 + g_a) * 96;
    const int mbase = (w % nwm) * 4096;
    const int qr0 = (wv << 4) + (gsl << 2);   // C-layout q-row base (+reg)
    const f32x4 zf = {0.f, 0.f, 0.f, 0.f};

    // ---------- phase 0: q full load, LN stats, LN+pack to 12 uint4 ----------
    uint4 qreg[12];
    {
        float qv[96];
        float sum = 0.f, ssq = 0.f;
        const float4* qr4 = (const float4*)(gq + rowbase);
#pragma unroll
        for (int i = 0; i < 24; ++i) {
            float4 x = qr4[i];
            qv[4 * i] = x.x; qv[4 * i + 1] = x.y;
            qv[4 * i + 2] = x.z; qv[4 * i + 3] = x.w;
            sum += (x.x + x.y) + (x.z + x.w);
            ssq += (x.x * x.x + x.y * x.y) + (x.z * x.z + x.w * x.w);
        }
        sum += __shfl_xor(sum, 1); ssq += __shfl_xor(ssq, 1);
        sum += __shfl_xor(sum, 2); ssq += __shfl_xor(ssq, 2);
        const float mu = sum * (1.f / 384.f);
        const float rs = rsqrtf(ssq * (1.f / 384.f) - mu * mu + 1e-5f);
        const float4* ga4 = (const float4*)(ggamma + s_a * 96);
        const float4* be4 = (const float4*)(gbeta + s_a * 96);
#pragma unroll
        for (int c6 = 0; c6 < 6; ++c6) {      // 16 channels per chunk
            float vals[16];
#pragma unroll
            for (int j = 0; j < 4; ++j) {
                float4 g = ga4[c6 * 4 + j];
                float4 b = be4[c6 * 4 + j];
                const int base = c6 * 16 + 4 * j;
                vals[4 * j + 0] = ((qv[base + 0] - mu) * rs * g.x + b.x) * 0.125f;
                vals[4 * j + 1] = ((qv[base + 1] - mu) * rs * g.y + b.y) * 0.125f;
                vals[4 * j + 2] = ((qv[base + 2] - mu) * rs * g.z + b.z) * 0.125f;
                vals[4 * j + 3] = ((qv[base + 3] - mu) * rs * g.w + b.w) * 0.125f;
            }
            qreg[2 * c6]     = pack8(vals);
            qreg[2 * c6 + 1] = pack8(vals + 8);
        }
    }
    uint4 kpf[2][2], vpf[2][2];
    load_pack(gk + rowbase, kpf[0]);
    load_pack(gv + rowbase, vpf[0]);

    // -------------------------- head loop --------------------------
#pragma unroll
    for (int n = 0; n < 6; ++n) {
        // issue next head's k/v prefetch FIRST (max loads in flight; the raw
        // barriers below never drain vmcnt, so these ride across the sync)
        if (n < 5) {
            load_pack(gk + rowbase + (n + 1) * 16, kpf[(n + 1) & 1]);
            load_pack(gv + rowbase + (n + 1) * 16, vpf[(n + 1) & 1]);
        }
        // stage Q (regs), K (prefetched), VT (prefetched, transposed, SV-swz)
        *(uint4*)(L + Q0 + SWZ(p_a, s_a * 2))     = qreg[2 * n];
        *(uint4*)(L + Q0 + SWZ(p_a, s_a * 2 + 1)) = qreg[2 * n + 1];
        *(uint4*)(L + K0 + SWZ(p_a, s_a * 2))     = kpf[n & 1][0];
        *(uint4*)(L + K0 + SWZ(p_a, s_a * 2 + 1)) = kpf[n & 1][1];
#pragma unroll
        for (int h = 0; h < 2; ++h) {
            FRAG u; u.u4 = vpf[n & 1][h];
#pragma unroll
            for (int c = 0; c < 8; ++c) {
                const int np_ = s_a * 16 + h * 8 + c;   // n' row of VT
                *(unsigned short*)(L + VT0 + (np_ << 7) +
                    (((p_a >> 3) ^ SVK(np_)) << 4) + ((p_a & 7) << 1)) = u.us[c];
            }
        }
        // C init = comb (bias+mask), L2/L3-resident
        f32x4 sacc[4];
        if (USE_COMB) {
            const float* cb = comb + (size_t)((w % nwm) * 6 + n) * 4096;
#pragma unroll
            for (int tile = 0; tile < 4; ++tile)
#pragma unroll
                for (int r = 0; r < 4; ++r)
                    sacc[tile][r] = cb[((qr0 + r) << 6) + (tile << 4) + r15];
        } else {
#pragma unroll
            for (int tile = 0; tile < 4; ++tile) {
                const int kpx = (tile << 4) + r15;
                const int ik = kpx >> 3, jk = kpx & 7;
#pragma unroll
                for (int r = 0; r < 4; ++r) {
                    const int q = qr0 + r;
                    sacc[tile][r] = gbt[(((q >> 3) - ik + 7) * 15 + ((q & 7) - jk + 7)) * 6 + n]
                                  + gmask[mbase + (q << 6) + kpx];
                }
            }
        }
        BAR_STAGE();                         // lgkm-only: staging visible

        // QK^T (C = comb)
        {
            FRAG a0, a1;
            a0.u4 = *(const uint4*)(L + Q0 + SWZ(wv * 16 + r15, gsl));
            a1.u4 = *(const uint4*)(L + Q0 + SWZ(wv * 16 + r15, 4 + gsl));
#pragma unroll
            for (int tile = 0; tile < 4; ++tile) {
                FRAG b0, b1;
                b0.u4 = *(const uint4*)(L + K0 + SWZ(tile * 16 + r15, gsl));
                b1.u4 = *(const uint4*)(L + K0 + SWZ(tile * 16 + r15, 4 + gsl));
                sacc[tile] = __builtin_amdgcn_mfma_f32_16x16x32_bf16(a0.s8, b0.s8, sacc[tile], 0, 0, 0);
                sacc[tile] = __builtin_amdgcn_mfma_f32_16x16x32_bf16(a1.s8, b1.s8, sacc[tile], 0, 0, 0);
            }
        }

        // softmax in place; P overlays Q0 (wave-private rows)
#pragma unroll
        for (int r = 0; r < 4; ++r) {
            const int q = qr0 + r;
            float mx = fmaxf(fmaxf(sacc[0][r], sacc[1][r]),
                             fmaxf(sacc[2][r], sacc[3][r]));
            mx = fmaxf(mx, __shfl_xor(mx, 1));
            mx = fmaxf(mx, __shfl_xor(mx, 2));
            mx = fmaxf(mx, __shfl_xor(mx, 4));
            mx = fmaxf(mx, __shfl_xor(mx, 8));
            float sm = 0.f;
#pragma unroll
            for (int tile = 0; tile < 4; ++tile) {
                sacc[tile][r] = __expf(sacc[tile][r] - mx);
                sm += sacc[tile][r];
            }
            sm += __shfl_xor(sm, 1);
            sm += __shfl_xor(sm, 2);
            sm += __shfl_xor(sm, 4);
            sm += __shfl_xor(sm, 8);
            const float inv = 1.0f / sm;
#pragma unroll
            for (int tile = 0; tile < 4; ++tile) {
                const int col = (tile << 4) + r15;
                *(unsigned short*)(L + Q0 + (q << 7) +
                                   (((col >> 3) ^ (q & 7)) << 4) + ((col & 7) << 1))
                    = f2b(sacc[tile][r] * inv);
            }
        }
        LGKM_FENCE();                        // P rows are wave-private

        // PV: A-frags = P (from Q0), B-frags = VT rows (SV swizzle)
        f32x4 oacc[4];
        {
            FRAG pa0, pa1;
            pa0.u4 = *(const uint4*)(L + Q0 + SWZ(wv * 16 + r15, gsl));
            pa1.u4 = *(const uint4*)(L + Q0 + SWZ(wv * 16 + r15, 4 + gsl));
#pragma unroll
            for (int ct = 0; ct < 4; ++ct) {
                const int nr = ct * 16 + r15;
                const int sv = SVK(nr);
                FRAG b0, b1;
                b0.u4 = *(const uint4*)(L + VT0 + (nr << 7) + ((gsl ^ sv) << 4));
                b1.u4 = *(const uint4*)(L + VT0 + (nr << 7) + (((4 + gsl) ^ sv) << 4));
                oacc[ct] = __builtin_amdgcn_mfma_f32_16x16x32_bf16(pa0.s8, b0.s8, zf, 0, 0, 0);
                oacc[ct] = __builtin_amdgcn_mfma_f32_16x16x32_bf16(pa1.s8, b1.s8, oacc[ct], 0, 0, 0);
            }
        }

        // pre[token = q*4 + s][ n*16 + hd ] into PR (208 B rows, wave-private)
#pragma unroll
        for (int ct = 0; ct < 4; ++ct)
#pragma unroll
            for (int r = 0; r < 4; ++r) {
                const int token = ((qr0 + r) << 2) + ct;
                *(unsigned short*)(L + PR0 + token * 208 + ((n << 4) + r15) * 2)
                    = f2b(oacc[ct][r]);
            }
        if (n < 5) BAR_WAR();                // cross-wave reads done; no drain
    }

    // ------ epilogue: deferred projection, 4 sequential M-tiles per wave ------
    LGKM_FENCE();                            // PR writes complete (same wave)
    {
        FRAG bw[3][6];
#pragma unroll
        for (int kk = 0; kk < 3; ++kk)
#pragma unroll
            for (int ct = 0; ct < 6; ++ct) {
                const int o = (ct << 4) + r15;
                const float4* wp = (const float4*)(gpw + o * 96 + kk * 32 + (gsl << 3));
                float4 w0 = wp[0], w1 = wp[1];
                float w8[8] = {w0.x, w0.y, w0.z, w0.w, w1.x, w1.y, w1.z, w1.w};
                bw[kk][ct].u4 = pack8(w8);
            }
        float pbv[6];
#pragma unroll
        for (int ct = 0; ct < 6; ++ct) pbv[ct] = gpb[(ct << 4) + r15];

#pragma unroll
        for (int mt = 0; mt < 4; ++mt) {
            const int rowA = (wv << 6) + (mt << 4) + r15;
            FRAG A[3];
#pragma unroll
            for (int kk = 0; kk < 3; ++kk)
                A[kk].u4 = *(const uint4*)(L + PR0 + rowA * 208 + kk * 64 + (gsl << 4));
            f32x4 acc[6];
#pragma unroll
            for (int ct = 0; ct < 6; ++ct) {
                acc[ct] = __builtin_amdgcn_mfma_f32_16x16x32_bf16(A[0].s8, bw[0][ct].s8, zf, 0, 0, 0);
                acc[ct] = __builtin_amdgcn_mfma_f32_16x16x32_bf16(A[1].s8, bw[1][ct].s8, acc[ct], 0, 0, 0);
                acc[ct] = __builtin_amdgcn_mfma_f32_16x16x32_bf16(A[2].s8, bw[2][ct].s8, acc[ct], 0, 0, 0);
            }
#pragma unroll
            for (int ct = 0; ct < 6; ++ct)
#pragma unroll
                for (int rr = 0; rr < 4; ++rr) {
                    const int token = (wv << 6) + (mt << 4) + (gsl << 2) + rr;
                    const int p = token >> 2, s = token & 3;
                    const int gsq = seq_of(p, s);
                    gout[((size_t)w * 256 + gsq) * 96 + (ct << 4) + r15]
                        = acc[ct][rr] + pbv[ct];
                }
        }
    }
}

extern "C" void kernel_launch(void* const* d_in, const int* in_sizes, int n_in,
                              void* d_out, int out_size, void* d_ws, size_t ws_size,
                              hipStream_t stream) {
    const float* gq     = (const float*)d_in[0];
    const float* gk     = (const float*)d_in[1];
    const float* gv     = (const float*)d_in[2];
    const float* gmask  = (const float*)d_in[3];
    const float* gbt    = (const float*)d_in[4];
    const float* ggamma = (const float*)d_in[5];
    const float* gbeta  = (const float*)d_in[6];
    const float* gpw    = (const float*)d_in[7];
    const float* gpb    = (const float*)d_in[8];
    float* gout = (float*)d_out;

    const int nw  = in_sizes[0] / (256 * 96);
    const int nwm = in_sizes[3] / (64 * 64);
    const size_t comb_bytes = (size_t)nwm * 6 * 4096 * sizeof(float);

    if (ws_size >= comb_bytes) {
        float* comb = (float*)d_ws;
        build_comb<<<nwm * 6, TPB, 0, stream>>>(gmask, gbt, comb);
        dwa_mfma<1><<<nw, TPB, 0, stream>>>(gq, gk, gv, gmask, gbt, ggamma, gbeta,
                                            gpw, gpb, gout, comb, nwm);
    } else {
        dwa_mfma<0><<<nw, TPB, 0, stream>>>(gq, gk, gv, gmask, gbt, ggamma, gbeta,
                                            gpw, gpb, gout, (const float*)nullptr, nwm);
    }
}

// Round 14
// 269.731 us; speedup vs baseline: 2.3038x; 1.0376x over previous
//
#include <hip/hip_runtime.h>
#include <hip/hip_bf16.h>

// DiagonalWindowAttention (v11 = r7 structure + TRUE double-buffered prefetch
// + de-unrolled head loop).
// One block per window (nw=2048), 256 thr, LB(256,2), LDS 80.9 KB (2 blk/CU).
//   prologue: LN stats (regs) from q; stage gamma/beta LDS; prefetch head-0
//             comb->saccA and raw q/k/v->bank A; lgkm barrier.
//   head n  : stage Q(LN now)/K (swz [64][64]) + VT (SV-swz) from CUR bank ->
//             prefetch comb(n+1)->sacc_NXT then raw qkv(n+1)->NXT bank ->
//             BAR(lgkm) -> QK^T MFMA (C = sacc_CUR, already in regs) ->
//             softmax -> P over Q0 (wave-private, fence) -> PV MFMA -> PR.
//             Loop: #pragma unroll 1 over 3 head-pairs (small code, I$-resident)
//   epilogue: deferred 256x96x96 projection from PR (per-wave M-tiles).
//
// token grouping: p = wh*8+ww, s = sh*2+sw, seq g = wh*32+sh*16+ww*2+sw

#define TPB 256

// LDS byte offsets
#define Q0   0        // [64][64] bf16 swizzled (8 KB); P overlays after QK^T
#define K0   8192
#define VT0  16384    // V^T per head (8 KB), SV-swizzled
#define PR0  24576    // pre[256 tokens][104 shorts] (208 B rows) = 53248 B
#define GA0  77824    // gamma fp32 [4][96] (1536 B)
#define BE0  79360    // beta  fp32 [4][96] (1536 B)
#define V_LDS 80896

typedef __attribute__((ext_vector_type(8))) short short8;
typedef __attribute__((ext_vector_type(4))) float f32x4;

union FRAG { uint4 u4; short8 s8; unsigned short us[8]; };

__device__ __forceinline__ int seq_of(int p, int s) {
    return ((p >> 3) << 5) | ((s >> 1) << 4) | ((p & 7) << 1) | (s & 1);
}

// swizzled byte address of 16B slot in a [64][64] bf16 tile (128B rows)
#define SWZ(row, slot) (((row) << 7) + ((((slot) ^ ((row) & 7))) << 4))
// VT swizzle key
#define SVK(n) (((n) ^ ((n) >> 3)) & 7)

#define LGKM_FENCE() do { \
    asm volatile("s_waitcnt lgkmcnt(0)" ::: "memory"); \
    __builtin_amdgcn_sched_barrier(0); } while (0)

// stage-complete barrier: drain LDS writes + sync; vmcnt stays in flight
#define BAR_STAGE() do { \
    asm volatile("s_waitcnt lgkmcnt(0)" ::: "memory"); \
    __builtin_amdgcn_sched_barrier(0); \
    __builtin_amdgcn_s_barrier(); \
    __builtin_amdgcn_sched_barrier(0); } while (0)

// end-of-iteration barrier: this wave's LDS reads already retired (data deps)
#define BAR_WAR() do { \
    __builtin_amdgcn_sched_barrier(0); \
    __builtin_amdgcn_s_barrier(); \
    __builtin_amdgcn_sched_barrier(0); } while (0)

__device__ __forceinline__ unsigned short f2b(float x) {
    union { __hip_bfloat16 h; unsigned short u; } z;
    z.h = __float2bfloat16(x);
    return z.u;
}

__device__ __forceinline__ uint4 pack8(const float* v) {
    union { uint4 u4; unsigned short us[8]; } z;
#pragma unroll
    for (int i = 0; i < 8; ++i) z.us[i] = f2b(v[i]);
    return z.u4;
}

// ---------------- pre-kernel: comb = mask + rel-pos bias ----------------
__global__ void build_comb(const float* __restrict__ gmask,
                           const float* __restrict__ gbt,
                           float* __restrict__ comb) {
    const int b = blockIdx.x;            // b = mi*6 + n
    const int mi = b / 6, n = b - mi * 6;
    const int t = threadIdx.x;
    const float* mrow = gmask + (size_t)mi * 4096;
    float* crow = comb + (size_t)b * 4096;
#pragma unroll
    for (int e = 0; e < 4096; e += TPB) {
        const int i = e + t;
        const int q = i >> 6, k = i & 63;
        const int idx = ((q >> 3) - (k >> 3) + 7) * 15 + ((q & 7) - (k & 7) + 7);
        crow[i] = mrow[i] + gbt[idx * 6 + n];
    }
}

// -------- raw prefetch: comb(NN)->SS (f32 regs), q/k/v(NN)->float4 banks -----
#define PREFETCH(NN, QQ, KK, VV, SS)                                           \
    {                                                                          \
        if (USE_COMB) {                                                        \
            const float* cb = comb + (size_t)((w % nwm) * 6 + (NN)) * 4096;    \
            _Pragma("unroll")                                                  \
            for (int tile = 0; tile < 4; ++tile)                               \
                _Pragma("unroll")                                              \
                for (int r = 0; r < 4; ++r)                                    \
                    SS[tile][r] = cb[((qr0 + r) << 6) + (tile << 4) + r15];    \
        } else {                                                               \
            _Pragma("unroll")                                                  \
            for (int tile = 0; tile < 4; ++tile) {                             \
                const int kpx = (tile << 4) + r15;                             \
                const int ik = kpx >> 3, jk = kpx & 7;                         \
                _Pragma("unroll")                                              \
                for (int r = 0; r < 4; ++r) {                                  \
                    const int q = qr0 + r;                                     \
                    SS[tile][r] = gbt[(((q >> 3) - ik + 7) * 15 +              \
                                      ((q & 7) - jk + 7)) * 6 + (NN)]          \
                                + gmask[mbase + (q << 6) + kpx];               \
                }                                                              \
            }                                                                  \
        }                                                                      \
        const float4* qp_ = (const float4*)(gq + rowbase + (NN) * 16);         \
        const float4* kp_ = (const float4*)(gk + rowbase + (NN) * 16);         \
        const float4* vp_ = (const float4*)(gv + rowbase + (NN) * 16);         \
        _Pragma("unroll")                                                      \
        for (int i = 0; i < 4; ++i) {                                          \
            QQ[i] = qp_[i]; KK[i] = kp_[i]; VV[i] = vp_[i];                    \
        }                                                                      \
    }

// -------- stage CUR bank into LDS: Q gets LN+scale+pack, K pack, VT swz ------
#define STAGE_QKV(NN, QQ, KK, VV)                                              \
    {                                                                          \
        const float* ga_ = s_ga + s_a * 96 + (NN) * 16;                        \
        const float* be_ = s_be + s_a * 96 + (NN) * 16;                        \
        float xq[16], xk[16], xv[16];                                          \
        _Pragma("unroll")                                                      \
        for (int i = 0; i < 4; ++i) {                                          \
            xq[4*i+0]=QQ[i].x; xq[4*i+1]=QQ[i].y; xq[4*i+2]=QQ[i].z; xq[4*i+3]=QQ[i].w; \
            xk[4*i+0]=KK[i].x; xk[4*i+1]=KK[i].y; xk[4*i+2]=KK[i].z; xk[4*i+3]=KK[i].w; \
            xv[4*i+0]=VV[i].x; xv[4*i+1]=VV[i].y; xv[4*i+2]=VV[i].z; xv[4*i+3]=VV[i].w; \
        }                                                                      \
        _Pragma("unroll")                                                      \
        for (int i = 0; i < 16; ++i)                                           \
            xq[i] = ((xq[i] - mu) * rs * ga_[i] + be_[i]) * 0.125f;            \
        *(uint4*)(L + Q0 + SWZ(p_a, s_a * 2))     = pack8(xq);                 \
        *(uint4*)(L + Q0 + SWZ(p_a, s_a * 2 + 1)) = pack8(xq + 8);             \
        *(uint4*)(L + K0 + SWZ(p_a, s_a * 2))     = pack8(xk);                 \
        *(uint4*)(L + K0 + SWZ(p_a, s_a * 2 + 1)) = pack8(xk + 8);             \
        _Pragma("unroll")                                                      \
        for (int c = 0; c < 16; ++c) {                                         \
            const int np_ = s_a * 16 + c;                                      \
            *(unsigned short*)(L + VT0 + (np_ << 7) +                          \
                (((p_a >> 3) ^ SVK(np_)) << 4) + ((p_a & 7) << 1)) = f2b(xv[c]); \
        }                                                                      \
    }

// -------- QK^T (C=SS in regs) -> softmax -> P -> PV -> PR --------
#define COMPUTE_HEAD(NN, SS)                                                   \
    {                                                                          \
        {                                                                      \
            FRAG a0, a1;                                                       \
            a0.u4 = *(const uint4*)(L + Q0 + SWZ(wv * 16 + r15, gsl));         \
            a1.u4 = *(const uint4*)(L + Q0 + SWZ(wv * 16 + r15, 4 + gsl));     \
            _Pragma("unroll")                                                  \
            for (int tile = 0; tile < 4; ++tile) {                             \
                FRAG b0, b1;                                                   \
                b0.u4 = *(const uint4*)(L + K0 + SWZ(tile * 16 + r15, gsl));   \
                b1.u4 = *(const uint4*)(L + K0 + SWZ(tile * 16 + r15, 4 + gsl)); \
                SS[tile] = __builtin_amdgcn_mfma_f32_16x16x32_bf16(a0.s8, b0.s8, SS[tile], 0, 0, 0); \
                SS[tile] = __builtin_amdgcn_mfma_f32_16x16x32_bf16(a1.s8, b1.s8, SS[tile], 0, 0, 0); \
            }                                                                  \
        }                                                                      \
        _Pragma("unroll")                                                      \
        for (int r = 0; r < 4; ++r) {                                          \
            const int q = qr0 + r;                                             \
            float mx = fmaxf(fmaxf(SS[0][r], SS[1][r]), fmaxf(SS[2][r], SS[3][r])); \
            mx = fmaxf(mx, __shfl_xor(mx, 1));                                 \
            mx = fmaxf(mx, __shfl_xor(mx, 2));                                 \
            mx = fmaxf(mx, __shfl_xor(mx, 4));                                 \
            mx = fmaxf(mx, __shfl_xor(mx, 8));                                 \
            float sm = 0.f;                                                    \
            _Pragma("unroll")                                                  \
            for (int tile = 0; tile < 4; ++tile) {                             \
                SS[tile][r] = __expf(SS[tile][r] - mx);                        \
                sm += SS[tile][r];                                             \
            }                                                                  \
            sm += __shfl_xor(sm, 1);                                           \
            sm += __shfl_xor(sm, 2);                                           \
            sm += __shfl_xor(sm, 4);                                           \
            sm += __shfl_xor(sm, 8);                                           \
            const float inv = 1.0f / sm;                                       \
            _Pragma("unroll")                                                  \
            for (int tile = 0; tile < 4; ++tile) {                             \
                const int col = (tile << 4) + r15;                             \
                *(unsigned short*)(L + Q0 + (q << 7) +                         \
                    (((col >> 3) ^ (q & 7)) << 4) + ((col & 7) << 1))          \
                    = f2b(SS[tile][r] * inv);                                  \
            }                                                                  \
        }                                                                      \
        LGKM_FENCE();                                                          \
        f32x4 oacc[4];                                                         \
        {                                                                      \
            FRAG pa0, pa1;                                                     \
            pa0.u4 = *(const uint4*)(L + Q0 + SWZ(wv * 16 + r15, gsl));        \
            pa1.u4 = *(const uint4*)(L + Q0 + SWZ(wv * 16 + r15, 4 + gsl));    \
            _Pragma("unroll")                                                  \
            for (int ct = 0; ct < 4; ++ct) {                                   \
                const int nr = ct * 16 + r15;                                  \
                const int sv = SVK(nr);                                        \
                FRAG b0, b1;                                                   \
                b0.u4 = *(const uint4*)(L + VT0 + (nr << 7) + ((gsl ^ sv) << 4)); \
                b1.u4 = *(const uint4*)(L + VT0 + (nr << 7) + (((4 + gsl) ^ sv) << 4)); \
                oacc[ct] = __builtin_amdgcn_mfma_f32_16x16x32_bf16(pa0.s8, b0.s8, zf, 0, 0, 0); \
                oacc[ct] = __builtin_amdgcn_mfma_f32_16x16x32_bf16(pa1.s8, b1.s8, oacc[ct], 0, 0, 0); \
            }                                                                  \
        }                                                                      \
        _Pragma("unroll")                                                      \
        for (int ct = 0; ct < 4; ++ct)                                         \
            _Pragma("unroll")                                                  \
            for (int r = 0; r < 4; ++r) {                                      \
                const int token = ((qr0 + r) << 2) + ct;                       \
                *(unsigned short*)(L + PR0 + token * 208 + (((NN) << 4) + r15) * 2) \
                    = f2b(oacc[ct][r]);                                        \
            }                                                                  \
    }

// ============================ main kernel ============================
template <int USE_COMB>
__global__ __launch_bounds__(TPB, 2)
void dwa_mfma(const float* __restrict__ gq,
              const float* __restrict__ gk,
              const float* __restrict__ gv,
              const float* __restrict__ gmask,
              const float* __restrict__ gbt,
              const float* __restrict__ ggamma,
              const float* __restrict__ gbeta,
              const float* __restrict__ gpw,
              const float* __restrict__ gpb,
              float* __restrict__ gout,
              const float* __restrict__ comb,
              int nwm)
{
    __shared__ __align__(16) unsigned char Lraw[V_LDS];
    char* L = (char*)Lraw;

    const int w = blockIdx.x;
    const int t = threadIdx.x;
    const int lane = t & 63, wv = t >> 6;
    const int r15 = lane & 15, gsl = lane >> 4;

    const int p_a = t >> 2, s_a = t & 3;
    const int g_a = seq_of(p_a, s_a);
    const size_t rowbase = ((size_t)w * 256 + g_a) * 96;
    const int mbase = (w % nwm) * 4096;
    const int qr0 = (wv << 4) + (gsl << 2);   // C-layout q-row base (+reg)
    const f32x4 zf = {0.f, 0.f, 0.f, 0.f};

    float* s_ga = (float*)(L + GA0);
    float* s_be = (float*)(L + BE0);

    // ---------- prologue: LN stats (regs only) + gamma/beta stage ----------
    float mu, rs;
    {
        const float4* qr4 = (const float4*)(gq + rowbase);
        float sum = 0.f, ssq = 0.f;
#pragma unroll
        for (int i = 0; i < 24; ++i) {
            float4 x = qr4[i];
            sum += (x.x + x.y) + (x.z + x.w);
            ssq += (x.x * x.x + x.y * x.y) + (x.z * x.z + x.w * x.w);
        }
        sum += __shfl_xor(sum, 1); ssq += __shfl_xor(ssq, 1);
        sum += __shfl_xor(sum, 2); ssq += __shfl_xor(ssq, 2);
        mu = sum * (1.f / 384.f);
        rs = rsqrtf(ssq * (1.f / 384.f) - mu * mu + 1e-5f);
    }
    for (int i = t; i < 384; i += TPB) {
        s_ga[i] = ggamma[i];
        s_be[i] = gbeta[i];
    }

    // banks (raw float4; conversion deferred to staging)
    float4 qA[4], kA[4], vA[4], qB[4], kB[4], vB[4];
    f32x4 sA[4], sB[4];

    PREFETCH(0, qA, kA, vA, sA);
    BAR_STAGE();                 // gamma/beta visible before first staging

    // -------- head loop: 3 iterations x 2 statically-banked heads --------
#pragma unroll 1
    for (int nh = 0; nh < 3; ++nh) {
        const int n0 = nh * 2;
        // ---- head n0: CUR = A, NXT = B ----
        STAGE_QKV(n0, qA, kA, vA);
        PREFETCH(n0 + 1, qB, kB, vB, sB);
        BAR_STAGE();
        COMPUTE_HEAD(n0, sA);
        BAR_WAR();
        // ---- head n0+1: CUR = B, NXT = A ----
        STAGE_QKV(n0 + 1, qB, kB, vB);
        if (nh < 2) PREFETCH(n0 + 2, qA, kA, vA, sA);
        BAR_STAGE();
        COMPUTE_HEAD(n0 + 1, sB);
        if (nh < 2) BAR_WAR();
    }

    // ------ epilogue: deferred projection, 4 sequential M-tiles per wave ------
    LGKM_FENCE();                            // PR writes complete (same wave)
    {
        FRAG bw[3][6];
#pragma unroll
        for (int kk = 0; kk < 3; ++kk)
#pragma unroll
            for (int ct = 0; ct < 6; ++ct) {
                const int o = (ct << 4) + r15;
                const float4* wp = (const float4*)(gpw + o * 96 + kk * 32 + (gsl << 3));
                float4 w0 = wp[0], w1 = wp[1];
                float w8[8] = {w0.x, w0.y, w0.z, w0.w, w1.x, w1.y, w1.z, w1.w};
                bw[kk][ct].u4 = pack8(w8);
            }
        float pbv[6];
#pragma unroll
        for (int ct = 0; ct < 6; ++ct) pbv[ct] = gpb[(ct << 4) + r15];

#pragma unroll
        for (int mt = 0; mt < 4; ++mt) {
            const int rowA = (wv << 6) + (mt << 4) + r15;
            FRAG A[3];
#pragma unroll
            for (int kk = 0; kk < 3; ++kk)
                A[kk].u4 = *(const uint4*)(L + PR0 + rowA * 208 + kk * 64 + (gsl << 4));
            f32x4 acc[6];
#pragma unroll
            for (int ct = 0; ct < 6; ++ct) {
                acc[ct] = __builtin_amdgcn_mfma_f32_16x16x32_bf16(A[0].s8, bw[0][ct].s8, zf, 0, 0, 0);
                acc[ct] = __builtin_amdgcn_mfma_f32_16x16x32_bf16(A[1].s8, bw[1][ct].s8, acc[ct], 0, 0, 0);
                acc[ct] = __builtin_amdgcn_mfma_f32_16x16x32_bf16(A[2].s8, bw[2][ct].s8, acc[ct], 0, 0, 0);
            }
#pragma unroll
            for (int ct = 0; ct < 6; ++ct)
#pragma unroll
                for (int rr = 0; rr < 4; ++rr) {
                    const int token = (wv << 6) + (mt << 4) + (gsl << 2) + rr;
                    const int p = token >> 2, s = token & 3;
                    const int gsq = seq_of(p, s);
                    gout[((size_t)w * 256 + gsq) * 96 + (ct << 4) + r15]
                        = acc[ct][rr] + pbv[ct];
                }
        }
    }
}

extern "C" void kernel_launch(void* const* d_in, const int* in_sizes, int n_in,
                              void* d_out, int out_size, void* d_ws, size_t ws_size,
                              hipStream_t stream) {
    const float* gq     = (const float*)d_in[0];
    const float* gk     = (const float*)d_in[1];
    const float* gv     = (const float*)d_in[2];
    const float* gmask  = (const float*)d_in[3];
    const float* gbt    = (const float*)d_in[4];
    const float* ggamma = (const float*)d_in[5];
    const float* gbeta  = (const float*)d_in[6];
    const float* gpw    = (const float*)d_in[7];
    const float* gpb    = (const float*)d_in[8];
    float* gout = (float*)d_out;

    const int nw  = in_sizes[0] / (256 * 96);
    const int nwm = in_sizes[3] / (64 * 64);
    const size_t comb_bytes = (size_t)nwm * 6 * 4096 * sizeof(float);

    if (ws_size >= comb_bytes) {
        float* comb = (float*)d_ws;
        build_comb<<<nwm * 6, TPB, 0, stream>>>(gmask, gbt, comb);
        dwa_mfma<1><<<nw, TPB, 0, stream>>>(gq, gk, gv, gmask, gbt, ggamma, gbeta,
                                            gpw, gpb, gout, comb, nwm);
    } else {
        dwa_mfma<0><<<nw, TPB, 0, stream>>>(gq, gk, gv, gmask, gbt, ggamma, gbeta,
                                            gpw, gpb, gout, (const float*)nullptr, nwm);
    }
}